// Round 3
// baseline (6248.669 us; speedup 1.0000x reference)
//
#include <hip/hip_runtime.h>

#define DECAY   0.6f
#define THRESH  0.6f
#define TSTEPS  28
#define NI      28
#define NH      512
#define BTOT    4096
#define BR      16
#define NTHREADS 512

__device__ __forceinline__ float sigmoidf_(float z) {
    return 1.0f / (1.0f + expf(-z));
}

// Persistent fused HNN kernel: each block owns BR batch rows for all T steps.
// Thread (rg,cg): rows r0..r0+3, cols j0..j0+3 (4x4 register tile).
// Row-value LDS reads are wave-uniform (broadcast, conflict-free); weight
// loads are lane-contiguous float4 (1 KB/wave coalesced). Spike-skip branch
// condition is wave-uniform -> s_cbranch, no divergence.
__global__ __launch_bounds__(NTHREADS, 2)
void hnn_fused(const float* __restrict__ x,
               const float* __restrict__ fc1s,   // snn_fc1 [28][512]
               const float* __restrict__ fc2s,   // snn_fc2 [1024][512]
               const float* __restrict__ fc1r,   // rnn_fc1 [28][512]
               const float* __restrict__ fc2r,   // rnn_fc2 [1024][512]
               const float* __restrict__ fv1,    // rnn_fv1 [512][512]
               const float* __restrict__ fv2,    // rnn_fv2 [512][512]
               const float* __restrict__ fcw,    // fc_w [10][1024]
               const float* __restrict__ fcb,    // fc_b [10]
               float* __restrict__ out)          // logits[4096*10] | h1y | h2y
{
    const int tid = threadIdx.x;
    const int rg  = tid >> 7;          // 0..3 (wave-uniform)
    const int cg  = tid & 127;         // 0..127
    const int j0  = cg << 2;           // column base
    const int r0  = rg << 2;           // row base within block
    const int rb  = blockIdx.x * BR;

    extern __shared__ char smem[];
    float* sh_x   = (float*)smem;                 // [BR][784]
    float* sh_h1y = sh_x + BR * 784;              // [BR][512]
    float* sh_h2y = sh_h1y + BR * NH;             // [BR][512]
    unsigned char* sh_spk = (unsigned char*)(sh_h2y + BR * NH); // [BR][512]

    for (int i = tid; i < BR * NH; i += NTHREADS) { sh_h1y[i] = 0.0f; sh_h2y[i] = 0.0f; }
    {   // stage this block's 16 x-rows (50 KB) into LDS once
        const float4* src = (const float4*)(x + (size_t)rb * 784);
        float4* dst = (float4*)sh_x;
        for (int i = tid; i < BR * 784 / 4; i += NTHREADS) dst[i] = src[i];
    }
    __syncthreads();

    float h1mem[4][4], h2mem[4][4], h2sum[4][4];
    #pragma unroll
    for (int m = 0; m < 4; ++m)
        #pragma unroll
        for (int c = 0; c < 4; ++c) { h1mem[m][c] = 0.f; h2mem[m][c] = 0.f; h2sum[m][c] = 0.f; }

    for (int t = 0; t < TSTEPS; ++t) {
        float accS[4][4], accR[4][4];
        #pragma unroll
        for (int m = 0; m < 4; ++m)
            #pragma unroll
            for (int c = 0; c < 4; ++c) { accS[m][c] = 0.f; accR[m][c] = 0.f; }

        // ---- layer 1: x_t @ fc1s and x_t @ fc1r (K=28); x_t[r][i] = x[r][i*28+t]
        #pragma unroll 4
        for (int k = 0; k < NI; ++k) {
            const float4 ws = *(const float4*)(fc1s + k * NH + j0);
            const float4 wr = *(const float4*)(fc1r + k * NH + j0);
            #pragma unroll
            for (int m = 0; m < 4; ++m) {
                const float xv = sh_x[(r0 + m) * 784 + k * 28 + t];
                accS[m][0] += xv * ws.x; accS[m][1] += xv * ws.y;
                accS[m][2] += xv * ws.z; accS[m][3] += xv * ws.w;
                accR[m][0] += xv * wr.x; accR[m][1] += xv * wr.y;
                accR[m][2] += xv * wr.z; accR[m][3] += xv * wr.w;
            }
        }
        // ---- layer 1: h1y_prev @ fv1 (K=512) into accR
        #pragma unroll 2
        for (int k4 = 0; k4 < NH; k4 += 4) {
            float4 hv[4];
            #pragma unroll
            for (int m = 0; m < 4; ++m)
                hv[m] = *(const float4*)(sh_h1y + (r0 + m) * NH + k4);
            #pragma unroll
            for (int kk = 0; kk < 4; ++kk) {
                const float4 w = *(const float4*)(fv1 + (k4 + kk) * NH + j0);
                #pragma unroll
                for (int m = 0; m < 4; ++m) {
                    const float h = ((const float*)&hv[m])[kk];
                    accR[m][0] += h * w.x; accR[m][1] += h * w.y;
                    accR[m][2] += h * w.z; accR[m][3] += h * w.w;
                }
            }
        }
        // membrane update, spike bytes, new h1y (regs)
        float h1y_new[4][4];
        #pragma unroll
        for (int m = 0; m < 4; ++m) {
            uchar4 sb;
            unsigned char sp[4];
            #pragma unroll
            for (int c = 0; c < 4; ++c) {
                float mem = h1mem[m][c];
                // prev spike recomputed from prev mem: spk = (mem > THRESH)
                mem = (mem > THRESH ? 0.0f : mem * DECAY) + accS[m][c];
                h1mem[m][c] = mem;
                sp[c] = (mem > THRESH) ? (unsigned char)1 : (unsigned char)0;
                h1y_new[m][c] = sigmoidf_(accR[m][c]);
            }
            sb.x = sp[0]; sb.y = sp[1]; sb.z = sp[2]; sb.w = sp[3];
            *(uchar4*)(sh_spk + (r0 + m) * NH + j0) = sb;  // read only after next 2 barriers
        }
        __syncthreads();          // all fv1 reads of old h1y done
        #pragma unroll
        for (int m = 0; m < 4; ++m) {
            float4 v; v.x = h1y_new[m][0]; v.y = h1y_new[m][1];
            v.z = h1y_new[m][2]; v.w = h1y_new[m][3];
            *(float4*)(sh_h1y + (r0 + m) * NH + j0) = v;
        }
        __syncthreads();          // h1y + spikes visible

        // ---- layer 2 ----
        #pragma unroll
        for (int m = 0; m < 4; ++m)
            #pragma unroll
            for (int c = 0; c < 4; ++c) { accS[m][c] = 0.f; accR[m][c] = 0.f; }

        // o1 spike half (K=512): wave-uniform conditional adds (skips loads too)
        #pragma unroll 1
        for (int k4 = 0; k4 < NH; k4 += 4) {
            unsigned u[4];
            #pragma unroll
            for (int m = 0; m < 4; ++m)
                u[m] = *(const unsigned*)(sh_spk + (r0 + m) * NH + k4);
            const unsigned any = u[0] | u[1] | u[2] | u[3];
            if (any == 0u) continue;
            #pragma unroll
            for (int kk = 0; kk < 4; ++kk) {
                if ((any >> (8 * kk)) & 0xffu) {
                    const float4 ws = *(const float4*)(fc2s + (k4 + kk) * NH + j0);
                    const float4 wr = *(const float4*)(fc2r + (k4 + kk) * NH + j0);
                    #pragma unroll
                    for (int m = 0; m < 4; ++m) {
                        if ((u[m] >> (8 * kk)) & 0xffu) {
                            accS[m][0] += ws.x; accS[m][1] += ws.y;
                            accS[m][2] += ws.z; accS[m][3] += ws.w;
                            accR[m][0] += wr.x; accR[m][1] += wr.y;
                            accR[m][2] += wr.z; accR[m][3] += wr.w;
                        }
                    }
                }
            }
        }
        // o1 h1y half (K=512): weight rows 512..1023
        #pragma unroll 1
        for (int k4 = 0; k4 < NH; k4 += 4) {
            float4 hv[4];
            #pragma unroll
            for (int m = 0; m < 4; ++m)
                hv[m] = *(const float4*)(sh_h1y + (r0 + m) * NH + k4);
            #pragma unroll
            for (int kk = 0; kk < 4; ++kk) {
                const float4 ws = *(const float4*)(fc2s + (NH + k4 + kk) * NH + j0);
                const float4 wr = *(const float4*)(fc2r + (NH + k4 + kk) * NH + j0);
                #pragma unroll
                for (int m = 0; m < 4; ++m) {
                    const float h = ((const float*)&hv[m])[kk];
                    accS[m][0] += h * ws.x; accS[m][1] += h * ws.y;
                    accS[m][2] += h * ws.z; accS[m][3] += h * ws.w;
                    accR[m][0] += h * wr.x; accR[m][1] += h * wr.y;
                    accR[m][2] += h * wr.z; accR[m][3] += h * wr.w;
                }
            }
        }
        // h2y_prev @ fv2 (K=512) into accR
        #pragma unroll 2
        for (int k4 = 0; k4 < NH; k4 += 4) {
            float4 hv[4];
            #pragma unroll
            for (int m = 0; m < 4; ++m)
                hv[m] = *(const float4*)(sh_h2y + (r0 + m) * NH + k4);
            #pragma unroll
            for (int kk = 0; kk < 4; ++kk) {
                const float4 w = *(const float4*)(fv2 + (k4 + kk) * NH + j0);
                #pragma unroll
                for (int m = 0; m < 4; ++m) {
                    const float h = ((const float*)&hv[m])[kk];
                    accR[m][0] += h * w.x; accR[m][1] += h * w.y;
                    accR[m][2] += h * w.z; accR[m][3] += h * w.w;
                }
            }
        }
        float h2y_new[4][4];
        #pragma unroll
        for (int m = 0; m < 4; ++m) {
            #pragma unroll
            for (int c = 0; c < 4; ++c) {
                float mem = h2mem[m][c];
                mem = (mem > THRESH ? 0.0f : mem * DECAY) + accS[m][c];
                h2mem[m][c] = mem;
                const float sp = (mem > THRESH) ? 1.0f : 0.0f;
                h2sum[m][c] += sp;
                h2y_new[m][c] = sigmoidf_(accR[m][c]);
            }
        }
        __syncthreads();          // all fv2 reads of old h2y done
        #pragma unroll
        for (int m = 0; m < 4; ++m) {
            float4 v; v.x = h2y_new[m][0]; v.y = h2y_new[m][1];
            v.z = h2y_new[m][2]; v.w = h2y_new[m][3];
            *(float4*)(sh_h2y + (r0 + m) * NH + j0) = v;
        }
        __syncthreads();
    }

    // ---- epilogue: h1y, h2y copies + logits ----
    const size_t L_OFF  = (size_t)BTOT * 10;
    const size_t H2_OFF = L_OFF + (size_t)BTOT * NH;
    #pragma unroll
    for (int m = 0; m < 4; ++m) {
        const int r = r0 + m;
        const int row = rb + r;
        *(float4*)(out + L_OFF  + (size_t)row * NH + j0) = *(const float4*)(sh_h1y + r * NH + j0);
        *(float4*)(out + H2_OFF + (size_t)row * NH + j0) = *(const float4*)(sh_h2y + r * NH + j0);
    }
    float* sh_sum = sh_x;   // reuse x slab for h2_sum/T (x no longer read)
    #pragma unroll
    for (int m = 0; m < 4; ++m)
        #pragma unroll
        for (int c = 0; c < 4; ++c)
            sh_sum[(r0 + m) * NH + j0 + c] = h2sum[m][c] * (1.0f / (float)TSTEPS);
    __syncthreads();
    if (tid < BR * 10) {
        const int r = tid / 10;
        const int c = tid % 10;
        float acc = fcb[c];
        for (int k = 0; k < NH; ++k) acc += sh_sum[r * NH + k] * fcw[c * 1024 + k];
        for (int k = 0; k < NH; ++k) acc += sh_h2y[r * NH + k] * fcw[c * 1024 + NH + k];
        out[(size_t)(rb + r) * 10 + c] = acc;
    }
}

extern "C" void kernel_launch(void* const* d_in, const int* in_sizes, int n_in,
                              void* d_out, int out_size, void* d_ws, size_t ws_size,
                              hipStream_t stream) {
    (void)in_sizes; (void)n_in; (void)out_size; (void)d_ws; (void)ws_size;
    const float* x    = (const float*)d_in[0];
    // d_in[1], d_in[2] (hidden1/hidden2) are zero-valued and unused by the reference math
    const float* fc1s = (const float*)d_in[3];
    const float* fc2s = (const float*)d_in[4];
    const float* fc1r = (const float*)d_in[5];
    const float* fc2r = (const float*)d_in[6];
    const float* fv1  = (const float*)d_in[7];
    const float* fv2  = (const float*)d_in[8];
    const float* fcw  = (const float*)d_in[9];
    const float* fcb  = (const float*)d_in[10];
    float* out = (float*)d_out;

    const size_t smem = (size_t)(BR * 784 + 2 * BR * NH) * sizeof(float) + (size_t)BR * NH; // 123904 B
    hipFuncSetAttribute(reinterpret_cast<const void*>(hnn_fused),
                        hipFuncAttributeMaxDynamicSharedMemorySize, (int)smem);
    hipLaunchKernelGGL(hnn_fused, dim3(BTOT / BR), dim3(NTHREADS), smem, stream,
                       x, fc1s, fc2s, fc1r, fc2r, fv1, fv2, fcw, fcb, out);
}